// Round 16
// baseline (43.412 us; speedup 1.0000x reference)
//
#include <hip/hip_runtime.h>

#define B_ 4
#define NB_ 131072
#define K_ 32
#define N_ (B_*NB_)
#define BK_ (B_*K_)        // 128
#define NACC 256           // k_accum blocks (64 per batch)
#define ABLK 64            // accum blocks per batch
#define PTS_PER_ACC 2048   // points per accum block

// ws float layout (no zeroing needed anywhere — every slot is plain-stored):
//   acc  [NACC][5*K_]   : per-block partial sums (cx,cy,cz,sig,cnt)
//   fin  [6][BK_]       : finalized cx,cy,cz,sig_mean,inv_cnt,inv2s2
//   part [2048][4]      : per-block partials from k_main
//   pk   [N_] float4    : packed per-point {cex,cey,cez,sigma}
//   inst8[N_] uchar     : per-point cluster id
#define ACC_OFF  0
#define FIN_OFF  (NACC*5*K_)             // 40960
#define PART_OFF (FIN_OFF + 6*BK_)       // 41728
#define PK_OFF   49920                   // float4-aligned
#define INST_OFF (PK_OFF + N_*4)         // float index; 4B-aligned uchar region

__global__ __launch_bounds__(1024) void k_accum(
    const float4* __restrict__ emb, const float* __restrict__ labels,
    float* __restrict__ ws)
{
    float4* pk = (float4*)(ws + PK_OFF);
    unsigned char* inst8 = (unsigned char*)(ws + INST_OFF);
    __shared__ float sacc[5*K_];
    int tid = threadIdx.x;
    if (tid < 5*K_) sacc[tid] = 0.f;
    __syncthreads();
    int start = blockIdx.x * PTS_PER_ACC;
    #pragma unroll
    for (int i = 0; i < PTS_PER_ACC/1024; ++i) {
        int n = start + i*1024 + tid;
        float4 e = emb[n];
        const float* lr = labels + (size_t)n*6;
        float c1 = lr[1];
        float2 c23 = *reinterpret_cast<const float2*>(lr + 2);
        int inst = ((int)lr[5]) & 31;
        float cex = e.x + (c1    - 384.f)/384.f;
        float cey = e.y + (c23.x - 384.f)/384.f;
        float cez = e.z + (c23.y - 384.f)/384.f;
        pk[n] = make_float4(cex, cey, cez, e.w);   // packed record for pass 2
        inst8[n] = (unsigned char)inst;
        atomicAdd(&sacc[0*K_+inst], cex);
        atomicAdd(&sacc[1*K_+inst], cey);
        atomicAdd(&sacc[2*K_+inst], cez);
        atomicAdd(&sacc[3*K_+inst], e.w);
        atomicAdd(&sacc[4*K_+inst], 1.0f);
    }
    __syncthreads();
    // plain store of this block's 160 partials (no atomics, no pre-zero)
    if (tid < 5*K_) ws[ACC_OFF + blockIdx.x*5*K_ + tid] = sacc[tid];
}

__global__ __launch_bounds__(256) void k_main(
    const float* __restrict__ seedp, float* __restrict__ ws,
    float4* __restrict__ part)
{
    __shared__ float s_raw[5*K_];
    __shared__ float s_fin[6*K_];    // cx,cy,cz,sig,inv,i2s
    int tid = threadIdx.x;
    int n = blockIdx.x * 256 + tid;
    int b = blockIdx.x >> 9;         // 512 blocks per batch
    const float4* pk = (const float4*)(ws + PK_OFF);
    const unsigned char* inst8 = (const unsigned char*)(ws + INST_OFF);

    // ---- phase A: per-block redundant finalize of this batch's partials ----
    if (tid < 5*K_) {
        float a = 0.f;
        const float* base = ws + ACC_OFF + (size_t)b*ABLK*5*K_ + tid;
        #pragma unroll 8
        for (int j = 0; j < ABLK; ++j) a += base[(size_t)j*5*K_];
        s_raw[tid] = a;
    }
    __syncthreads();
    if (tid < K_) {
        float cnt = fmaxf(s_raw[4*K_+tid], 1.f);
        float inv = 1.f / cnt;
        float cx = s_raw[0*K_+tid] * inv;
        float cy = s_raw[1*K_+tid] * inv;
        float cz = s_raw[2*K_+tid] * inv;
        float sg = s_raw[3*K_+tid] * inv;
        float i2s = 1.f / (2.f*sg*sg);
        s_fin[0*K_+tid] = cx;
        s_fin[1*K_+tid] = cy;
        s_fin[2*K_+tid] = cz;
        s_fin[3*K_+tid] = sg;
        s_fin[4*K_+tid] = inv;
        s_fin[5*K_+tid] = i2s;
        if ((blockIdx.x & 511) == 0) {      // one block per batch persists fin
            float* fin = ws + FIN_OFF;
            fin[0*BK_ + b*K_+tid] = cx;
            fin[1*BK_ + b*K_+tid] = cy;
            fin[2*BK_ + b*K_+tid] = cz;
            fin[3*BK_ + b*K_+tid] = sg;
            fin[4*BK_ + b*K_+tid] = inv;
            fin[5*BK_ + b*K_+tid] = i2s;
        }
    }
    __syncthreads();

    // ---- phase B: per-point pass (dense packed loads: 21 B/point) ----
    float4 p4 = pk[n];
    float sd = seedp[n];
    int inst = (int)inst8[n];
    float cex = p4.x, cey = p4.y, cez = p4.z, sigma = p4.w;

    unsigned bestpk = 0xffffffffu;
    float msum = 0.f;
    #pragma unroll
    for (int k = 0; k < K_; ++k) {
        float dx = cex - s_fin[0*K_+k];
        float dy = cey - s_fin[1*K_+k];
        float dz = cez - s_fin[2*K_+k];
        float d2 = dx*dx + dy*dy + dz*dz;
        // packed argmin: d2>=0 so float bits are order-preserving; low 5 bits
        // carry k so exact ties resolve to the first (lowest-k) min like jnp.argmin
        unsigned pkb = (__float_as_uint(d2) & ~31u) | (unsigned)k;
        bestpk = min(bestpk, pkb);
        float arg = d2 * s_fin[5*K_+k];
        // true log1p(-e^-arg) for arg>=15 is in (-3.2e-7, 0]: contributes 0
        if (__any(arg < 15.f)) {
            float argc = fminf(fmaxf(arg, 1e-7f), 100.f);
            float p = __expf(-argc);
            float l1p = __logf(1.f - p);        // == log1p(-p), 1-p exact (Sterbenz)
            msum += (arg < 15.f) ? l1p : 0.f;
        }
    }
    int bi = (int)(bestpk & 31u);

    // k = inst term, recomputed once (replaces per-k selects in the loop)
    float dxI = cex - s_fin[0*K_+inst];
    float dyI = cey - s_fin[1*K_+inst];
    float dzI = cez - s_fin[2*K_+inst];
    float d2I = dxI*dxI + dyI*dyI + dzI*dzI;
    float argRawI = d2I * s_fin[5*K_+inst];
    float argI = fminf(fmaxf(argRawI, 1e-7f), 100.f);
    float pI = __expf(-argI);
    if (argRawI < 15.f) msum -= __logf(1.f - pI);   // undo its l1p from the loop
    msum -= argI;                                    // onehot * (-arg)

    float inv_in = s_fin[4*K_+inst];
    float smoothv = fabsf(sigma - s_fin[3*K_+inst]) * inv_in;
    float dsd = sd - pI;
    float seedv = dsd*dsd*inv_in;
    float accv = (bi == inst) ? 1.0f : 0.0f;

    // block reduction: wave shuffle then cross-wave via LDS
    float v0 = msum, v1 = smoothv, v2 = seedv, v3 = accv;
    for (int off = 32; off; off >>= 1) {
        v0 += __shfl_down(v0, off);
        v1 += __shfl_down(v1, off);
        v2 += __shfl_down(v2, off);
        v3 += __shfl_down(v3, off);
    }
    __shared__ float sred[4][4];
    int wid = tid >> 6, lane = tid & 63;
    if (lane == 0) { sred[wid][0]=v0; sred[wid][1]=v1; sred[wid][2]=v2; sred[wid][3]=v3; }
    __syncthreads();
    if (tid == 0) {
        float r0=0.f,r1=0.f,r2=0.f,r3=0.f;
        for (int w = 0; w < 4; ++w) { r0+=sred[w][0]; r1+=sred[w][1]; r2+=sred[w][2]; r3+=sred[w][3]; }
        part[blockIdx.x] = make_float4(r0, r1, r2, r3);   // plain store, no atomics
    }
}

__global__ __launch_bounds__(256) void k_final(
    const float* __restrict__ ws, const float* __restrict__ part,
    float* __restrict__ out)
{
    int tid = threadIdx.x;

    // --- reduce per-block partials: 16 (f,b) pairs, 16 threads each ---
    int pair = tid >> 4;          // 0..15
    int lane16 = tid & 15;
    int f = pair >> 2, b = pair & 3;
    float v = 0.f;
    #pragma unroll
    for (int j = 0; j < 32; ++j) {
        int blk = b*512 + lane16*32 + j;
        v += part[blk*4 + f];
    }
    v += __shfl_down(v, 8);
    v += __shfl_down(v, 4);
    v += __shfl_down(v, 2);
    v += __shfl_down(v, 1);
    __shared__ float S[16];       // S[f*4+b]
    if (lane16 == 0) S[pair] = v;

    // --- inter-loss hinge over center pairs ---
    float h = 0.f;
    for (int idx = tid; idx < B_*K_*K_; idx += 256) {
        int bb = idx >> 10;
        int ij = idx & 1023;
        int i = ij >> 5, j = ij & 31;
        if (i != j) {
            const float* fin = ws + FIN_OFF;
            float dx = fin[0*BK_ + bb*K_+i] - fin[0*BK_ + bb*K_+j];
            float dy = fin[1*BK_ + bb*K_+i] - fin[1*BK_ + bb*K_+j];
            float dz = fin[2*BK_ + bb*K_+i] - fin[2*BK_ + bb*K_+j];
            float cd2 = dx*dx + dy*dy + dz*dz;
            float d = sqrtf(cd2);
            float hg = fmaxf(0.f, 1.0f - d);
            h += hg*hg;
        }
    }
    for (int off = 32; off; off >>= 1) h += __shfl_down(h, off);
    __shared__ float sh[4];
    int wid = tid >> 6, lane = tid & 63;
    if (lane == 0) sh[wid] = h;
    __syncthreads();

    if (tid == 0) {
        float ht = sh[0]+sh[1]+sh[2]+sh[3];
        float loss = 0.f;
        for (int bb = 0; bb < B_; ++bb) {
            float mask_l   = -S[0*4+bb] / (float)NB_ / (float)K_;
            float smooth_l =  S[1*4+bb] / (float)K_;
            float seed_l   =  S[2*4+bb] / (float)K_;
            loss += mask_l + smooth_l + seed_l;
        }
        loss = loss / (float)B_ + ht / (2.0f * (float)(K_*(K_-1)) * (float)B_);
        float acc = (S[3*4+0]+S[3*4+1]+S[3*4+2]+S[3*4+3]) / (float)N_;
        out[0] = loss;
        out[1] = acc;
    }
}

extern "C" void kernel_launch(void* const* d_in, const int* in_sizes, int n_in,
                              void* d_out, int out_size, void* d_ws, size_t ws_size,
                              hipStream_t stream)
{
    const float4* emb    = (const float4*)d_in[0];
    const float*  seedp  = (const float*)d_in[1];
    const float*  labels = (const float*)d_in[2];
    float* ws  = (float*)d_ws;
    float* out = (float*)d_out;

    // 3 dispatches; no memset needed (all ws regions fully written by plain stores)
    k_accum <<<NACC,   1024, 0, stream>>>(emb, labels, ws);
    k_main  <<<N_/256, 256,  0, stream>>>(seedp, ws, (float4*)(ws + PART_OFF));
    k_final <<<1,      256,  0, stream>>>(ws, ws + PART_OFF, out);
}

// Round 17
// 42.620 us; speedup vs baseline: 1.0186x; 1.0186x over previous
//
#include <hip/hip_runtime.h>

#define B_ 4
#define NB_ 131072
#define K_ 32
#define N_ (B_*NB_)
#define BK_ (B_*K_)        // 128
#define NACC 256           // k_accum blocks (64 per batch)
#define ABLK 64            // accum blocks per batch
#define PTS_PER_ACC 2048   // points per accum block

// ws float layout (no zeroing needed anywhere — every slot is plain-stored):
//   acc  [NACC][5*K_]   : per-block partial sums (cx,cy,cz,sig,cnt)
//   fin  [6][BK_]       : finalized cx,cy,cz,sig_mean,inv_cnt,inv2s2
//   part [2048][4]      : per-block partials from k_main
#define ACC_OFF  0
#define FIN_OFF  (NACC*5*K_)             // 40960
#define PART_OFF (FIN_OFF + 6*BK_)       // 41728

__global__ __launch_bounds__(1024) void k_accum(
    const float4* __restrict__ emb, const float* __restrict__ labels,
    float* __restrict__ ws)
{
    __shared__ float sacc[5*K_];
    int tid = threadIdx.x;
    if (tid < 5*K_) sacc[tid] = 0.f;
    __syncthreads();
    int start = blockIdx.x * PTS_PER_ACC;
    #pragma unroll
    for (int i = 0; i < PTS_PER_ACC/1024; ++i) {
        int n = start + i*1024 + tid;
        float4 e = emb[n];
        const float* lr = labels + (size_t)n*6;
        float c1 = lr[1];
        float2 c23 = *reinterpret_cast<const float2*>(lr + 2);
        int inst = ((int)lr[5]) & 31;
        float cex = e.x + (c1    - 384.f)/384.f;
        float cey = e.y + (c23.x - 384.f)/384.f;
        float cez = e.z + (c23.y - 384.f)/384.f;
        atomicAdd(&sacc[0*K_+inst], cex);
        atomicAdd(&sacc[1*K_+inst], cey);
        atomicAdd(&sacc[2*K_+inst], cez);
        atomicAdd(&sacc[3*K_+inst], e.w);
        atomicAdd(&sacc[4*K_+inst], 1.0f);
    }
    __syncthreads();
    // plain store of this block's 160 partials (no atomics, no pre-zero)
    if (tid < 5*K_) ws[ACC_OFF + blockIdx.x*5*K_ + tid] = sacc[tid];
}

__global__ __launch_bounds__(256) void k_main(
    const float4* __restrict__ emb, const float* __restrict__ seedp,
    const float* __restrict__ labels, float* __restrict__ ws,
    float4* __restrict__ part)
{
    __shared__ float s_raw[5*K_];
    __shared__ float s_fin[6*K_];    // cx,cy,cz,sig,inv,i2s
    int tid = threadIdx.x;
    int n = blockIdx.x * 256 + tid;
    int b = blockIdx.x >> 9;         // 512 blocks per batch

    // ---- phase A: per-block redundant finalize of this batch's partials ----
    if (tid < 5*K_) {
        float a = 0.f;
        const float* base = ws + ACC_OFF + (size_t)b*ABLK*5*K_ + tid;
        #pragma unroll 8
        for (int j = 0; j < ABLK; ++j) a += base[(size_t)j*5*K_];
        s_raw[tid] = a;
    }
    __syncthreads();
    if (tid < K_) {
        float cnt = fmaxf(s_raw[4*K_+tid], 1.f);
        float inv = 1.f / cnt;
        float cx = s_raw[0*K_+tid] * inv;
        float cy = s_raw[1*K_+tid] * inv;
        float cz = s_raw[2*K_+tid] * inv;
        float sg = s_raw[3*K_+tid] * inv;
        float i2s = 1.f / (2.f*sg*sg);
        s_fin[0*K_+tid] = cx;
        s_fin[1*K_+tid] = cy;
        s_fin[2*K_+tid] = cz;
        s_fin[3*K_+tid] = sg;
        s_fin[4*K_+tid] = inv;
        s_fin[5*K_+tid] = i2s;
        if ((blockIdx.x & 511) == 0) {      // one block per batch persists fin
            float* fin = ws + FIN_OFF;
            fin[0*BK_ + b*K_+tid] = cx;
            fin[1*BK_ + b*K_+tid] = cy;
            fin[2*BK_ + b*K_+tid] = cz;
            fin[3*BK_ + b*K_+tid] = sg;
            fin[4*BK_ + b*K_+tid] = inv;
            fin[5*BK_ + b*K_+tid] = i2s;
        }
    }
    __syncthreads();

    // ---- phase B: per-point pass ----
    float4 e = emb[n];
    float sd = seedp[n];
    const float* lr = labels + (size_t)n*6;
    float c1 = lr[1];
    float2 c23 = *reinterpret_cast<const float2*>(lr + 2);
    int inst = ((int)lr[5]) & 31;
    float cex = e.x + (c1    - 384.f)/384.f;
    float cey = e.y + (c23.x - 384.f)/384.f;
    float cez = e.z + (c23.y - 384.f)/384.f;
    float sigma = e.w;

    unsigned bestpk = 0xffffffffu;
    float msum = 0.f;
    #pragma unroll
    for (int k = 0; k < K_; ++k) {
        float dx = cex - s_fin[0*K_+k];
        float dy = cey - s_fin[1*K_+k];
        float dz = cez - s_fin[2*K_+k];
        float d2 = dx*dx + dy*dy + dz*dz;
        // packed argmin: d2>=0 so float bits are order-preserving; low 5 bits
        // carry k so exact ties resolve to the first (lowest-k) min like jnp.argmin
        unsigned pk = (__float_as_uint(d2) & ~31u) | (unsigned)k;
        bestpk = min(bestpk, pk);
        float arg = d2 * s_fin[5*K_+k];
        // true log1p(-e^-arg) for arg>=15 is in (-3.2e-7, 0]: contributes 0
        if (__any(arg < 15.f)) {
            float argc = fminf(fmaxf(arg, 1e-7f), 100.f);
            float p = __expf(-argc);
            float l1p = __logf(1.f - p);        // == log1p(-p), 1-p exact (Sterbenz)
            msum += (arg < 15.f) ? l1p : 0.f;
        }
    }
    int bi = (int)(bestpk & 31u);

    // k = inst term, recomputed once (replaces per-k selects in the loop)
    float dxI = cex - s_fin[0*K_+inst];
    float dyI = cey - s_fin[1*K_+inst];
    float dzI = cez - s_fin[2*K_+inst];
    float d2I = dxI*dxI + dyI*dyI + dzI*dzI;
    float argRawI = d2I * s_fin[5*K_+inst];
    float argI = fminf(fmaxf(argRawI, 1e-7f), 100.f);
    float pI = __expf(-argI);
    if (argRawI < 15.f) msum -= __logf(1.f - pI);   // undo its l1p from the loop
    msum -= argI;                                    // onehot * (-arg)

    float inv_in = s_fin[4*K_+inst];
    float smoothv = fabsf(sigma - s_fin[3*K_+inst]) * inv_in;
    float dsd = sd - pI;
    float seedv = dsd*dsd*inv_in;
    float accv = (bi == inst) ? 1.0f : 0.0f;

    // block reduction: wave shuffle then cross-wave via LDS
    float v0 = msum, v1 = smoothv, v2 = seedv, v3 = accv;
    for (int off = 32; off; off >>= 1) {
        v0 += __shfl_down(v0, off);
        v1 += __shfl_down(v1, off);
        v2 += __shfl_down(v2, off);
        v3 += __shfl_down(v3, off);
    }
    __shared__ float sred[4][4];
    int wid = tid >> 6, lane = tid & 63;
    if (lane == 0) { sred[wid][0]=v0; sred[wid][1]=v1; sred[wid][2]=v2; sred[wid][3]=v3; }
    __syncthreads();
    if (tid == 0) {
        float r0=0.f,r1=0.f,r2=0.f,r3=0.f;
        for (int w = 0; w < 4; ++w) { r0+=sred[w][0]; r1+=sred[w][1]; r2+=sred[w][2]; r3+=sred[w][3]; }
        part[blockIdx.x] = make_float4(r0, r1, r2, r3);   // plain store, no atomics
    }
}

__global__ __launch_bounds__(256) void k_final(
    const float* __restrict__ ws, const float* __restrict__ part,
    float* __restrict__ out)
{
    int tid = threadIdx.x;

    // --- reduce per-block partials: 16 (f,b) pairs, 16 threads each ---
    int pair = tid >> 4;          // 0..15
    int lane16 = tid & 15;
    int f = pair >> 2, b = pair & 3;
    float v = 0.f;
    #pragma unroll
    for (int j = 0; j < 32; ++j) {
        int blk = b*512 + lane16*32 + j;
        v += part[blk*4 + f];
    }
    v += __shfl_down(v, 8);
    v += __shfl_down(v, 4);
    v += __shfl_down(v, 2);
    v += __shfl_down(v, 1);
    __shared__ float S[16];       // S[f*4+b]
    if (lane16 == 0) S[pair] = v;

    // --- inter-loss hinge over center pairs ---
    float h = 0.f;
    for (int idx = tid; idx < B_*K_*K_; idx += 256) {
        int bb = idx >> 10;
        int ij = idx & 1023;
        int i = ij >> 5, j = ij & 31;
        if (i != j) {
            const float* fin = ws + FIN_OFF;
            float dx = fin[0*BK_ + bb*K_+i] - fin[0*BK_ + bb*K_+j];
            float dy = fin[1*BK_ + bb*K_+i] - fin[1*BK_ + bb*K_+j];
            float dz = fin[2*BK_ + bb*K_+i] - fin[2*BK_ + bb*K_+j];
            float cd2 = dx*dx + dy*dy + dz*dz;
            float d = sqrtf(cd2);
            float hg = fmaxf(0.f, 1.0f - d);
            h += hg*hg;
        }
    }
    for (int off = 32; off; off >>= 1) h += __shfl_down(h, off);
    __shared__ float sh[4];
    int wid = tid >> 6, lane = tid & 63;
    if (lane == 0) sh[wid] = h;
    __syncthreads();

    if (tid == 0) {
        float ht = sh[0]+sh[1]+sh[2]+sh[3];
        float loss = 0.f;
        for (int bb = 0; bb < B_; ++bb) {
            float mask_l   = -S[0*4+bb] / (float)NB_ / (float)K_;
            float smooth_l =  S[1*4+bb] / (float)K_;
            float seed_l   =  S[2*4+bb] / (float)K_;
            loss += mask_l + smooth_l + seed_l;
        }
        loss = loss / (float)B_ + ht / (2.0f * (float)(K_*(K_-1)) * (float)B_);
        float acc = (S[3*4+0]+S[3*4+1]+S[3*4+2]+S[3*4+3]) / (float)N_;
        out[0] = loss;
        out[1] = acc;
    }
}

extern "C" void kernel_launch(void* const* d_in, const int* in_sizes, int n_in,
                              void* d_out, int out_size, void* d_ws, size_t ws_size,
                              hipStream_t stream)
{
    const float4* emb    = (const float4*)d_in[0];
    const float*  seedp  = (const float*)d_in[1];
    const float*  labels = (const float*)d_in[2];
    float* ws  = (float*)d_ws;
    float* out = (float*)d_out;

    // 3 dispatches; no memset needed (all ws regions fully written by plain stores)
    k_accum <<<NACC,   1024, 0, stream>>>(emb, labels, ws);
    k_main  <<<N_/256, 256,  0, stream>>>(emb, seedp, labels, ws,
                                          (float4*)(ws + PART_OFF));
    k_final <<<1,      256,  0, stream>>>(ws, ws + PART_OFF, out);
}